// Round 6
// baseline (174.322 us; speedup 1.0000x reference)
//
#include <hip/hip_runtime.h>
#include <hip/hip_bf16.h>
#include <cstdint>

// Problem constants
#define B_DIM 2048
#define H_DIM 1024
#define K_DIM 2048   // 2*H  (input | hidden)
#define N_DIM 4096   // 4*H  (gates, interleaved n' = 4*h + gate)

typedef unsigned short u16;
typedef __attribute__((ext_vector_type(8))) short bf16x8;
typedef __attribute__((ext_vector_type(8))) unsigned short u16x8;
typedef __attribute__((ext_vector_type(16))) float f32x16;

__device__ __forceinline__ u16 f2bf(float f) {
    unsigned int u = __float_as_uint(f);
    u += 0x7FFFu + ((u >> 16) & 1u);   // round-to-nearest-even
    return (u16)(u >> 16);
}

__device__ __forceinline__ float sigmoid_f(float x) {
    return 1.0f / (1.0f + __expf(-x));
}

// tanh via exp, saturating form (no inf/inf NaN at large |x|)
__device__ __forceinline__ float tanh_f(float x) {
    float e = __expf(2.0f * x);
    return 1.0f - 2.0f / (e + 1.0f);
}

// async global->LDS 16B per lane. LDS dest is wave-uniform base + lane*16.
__device__ __forceinline__ void async16(const u16* g, u16* l) {
    __builtin_amdgcn_global_load_lds(
        (const __attribute__((address_space(1))) unsigned int*)g,
        (__attribute__((address_space(3))) unsigned int*)l,
        16, 0, 0);
}

// ---------------------------------------------------------------------------
// Kernel 1: all packing in ONE launch.
// Region A (blocks 0..4095):        A = [input|hidden] bf16 2048x2048
// Region B (blocks 4096..8191):     Bt[n'][k], n' = 4h+g (f,i,o,c)
// Region bias (blocks 8192..8207):  bias_il[4h+g] = b_g[h]
// ---------------------------------------------------------------------------
__global__ __launch_bounds__(256) void pack_all(
    const float* __restrict__ input, const float* __restrict__ hidden,
    const float* __restrict__ w_f, const float* __restrict__ w_i,
    const float* __restrict__ w_o, const float* __restrict__ w_c,
    const float* __restrict__ u_f, const float* __restrict__ u_i,
    const float* __restrict__ u_o, const float* __restrict__ u_c,
    const float* __restrict__ b1, const float* __restrict__ b2,
    const float* __restrict__ b3, const float* __restrict__ b4,
    u16* __restrict__ A, u16* __restrict__ Bt, float* __restrict__ bias_il) {
    __shared__ float tile[32][65];
    const int blk = blockIdx.x;
    const int t = threadIdx.x;

    if (blk < 4096) {
        // ---- pack_A ----
        int idx = (blk * 256 + t) * 4;
        int m = idx >> 11;
        int k = idx & (K_DIM - 1);
        const float* src = (k < H_DIM) ? (input + (size_t)m * H_DIM + k)
                                       : (hidden + (size_t)m * H_DIM + (k - H_DIM));
        float4 v = *(const float4*)src;
        ushort4 o;
        o.x = f2bf(v.x); o.y = f2bf(v.y); o.z = f2bf(v.z); o.w = f2bf(v.w);
        *(ushort4*)(A + idx) = o;
    } else if (blk < 8192) {
        // ---- pack_B: 32h x 64k tile transpose ----
        int b2i = blk - 4096;
        int z = b2i >> 9;
        int rem = b2i & 511;
        int hx = rem & 31;
        int ky = rem >> 5;
        const float* M;
        switch (z) {
            case 0: M = w_f; break;
            case 1: M = w_i; break;
            case 2: M = w_o; break;
            case 3: M = w_c; break;
            case 4: M = u_f; break;
            case 5: M = u_i; break;
            case 6: M = u_o; break;
            default: M = u_c; break;
        }
        const int g = z & 3;
        const int half = z >> 2;
        const int h0 = hx * 32;
        const int k0 = ky * 64;
#pragma unroll
        for (int it = 0; it < 2; it++) {
            int kl = (t >> 3) + it * 32;
            int hl = (t & 7) * 4;
            float4 v = *(const float4*)(M + (size_t)(k0 + kl) * H_DIM + h0 + hl);
            tile[hl + 0][kl] = v.x;
            tile[hl + 1][kl] = v.y;
            tile[hl + 2][kl] = v.z;
            tile[hl + 3][kl] = v.w;
        }
        __syncthreads();
        int hl = t >> 3;
        int ko = (t & 7) * 8;
        u16x8 o;
#pragma unroll
        for (int q = 0; q < 8; q++) o[q] = f2bf(tile[hl][ko + q]);
        size_t n = 4 * (size_t)(h0 + hl) + g;
        *(u16x8*)(Bt + n * K_DIM + half * H_DIM + k0 + ko) = o;
    } else {
        // ---- pack_bias ----
        int idx = (blk - 8192) * 256 + t;
        int h = idx >> 2, g = idx & 3;
        const float* b = (g == 0) ? b1 : (g == 1) ? b2 : (g == 2) ? b3 : b4;
        bias_il[idx] = b[h];
    }
}

// ---------------------------------------------------------------------------
// Kernel 2: fused GEMM + LSTM epilogue.  BM=BN=128, BK=64 (two 32-k slabs),
// MFMA 32x32x16 (2x FLOPs per LDS fragment byte vs 16x16x32 -> K-loop LDS
// traffic 96KB -> 64KB per block-iter; we measured R5 as LDS-BW-bound).
// Barrier shape kept from R5 (stage -> barrier -> compute -> barrier; R4's
// issue/drain separation broke correctness).
// Per wave: 64x64 tile = 2x2 MFMA tiles of 32x32, acc 16 f32 each.
// ---------------------------------------------------------------------------
#define BM 128
#define BN 128
#define BK 64
#define SL (64 * 32)   // u16 elements per half-slab issue offset

__global__ __launch_bounds__(256, 2) void gemm_fused(
    const u16* __restrict__ A, const u16* __restrict__ Bt,
    const float* __restrict__ bias_il, const float* __restrict__ pre_cell,
    const float* __restrict__ mask, float* __restrict__ out) {
    __shared__ char smem[33280];
    u16* AsL = (u16*)smem;                 // A k-lo slab: 128x32 = 8KB
    u16* AsH = (u16*)(smem + 8192);        // A k-hi slab
    u16* BsL = (u16*)(smem + 16384);       // B k-lo slab
    u16* BsH = (u16*)(smem + 24576);       // B k-hi slab
    float* et = (float*)smem;              // epilogue reuse: [128][65] f32

    const int t = threadIdx.x;
    const int w = t >> 6, l = t & 63;
    const int m0 = blockIdx.y * BM;
    const int n0 = blockIdx.x * BN;
    const int wr = w >> 1;    // wave row in 2x2
    const int wc = w & 1;     // wave col
    const int ln = l & 31;    // m (A) / n (B) within 32
    const int hi = l >> 5;    // k-group 0..1 -> k-chunk of 8

    // staging: lane l of wave w covers row w*16+(l>>2) (+64 for 2nd issue),
    // k-offset (l&3)*8 within a 32-k slab. LDS addr = uniform base + 16*lane.
    const int sr = w * 16 + (l >> 2);
    const int sc = (l & 3) * 8;
    const u16* Ag0 = A + (size_t)(m0 + sr) * K_DIM + sc;
    const u16* Ag1 = Ag0 + (size_t)64 * K_DIM;
    const u16* Bg0 = Bt + (size_t)(n0 + sr) * K_DIM + sc;
    const u16* Bg1 = Bg0 + (size_t)64 * K_DIM;
    const int soff = sr * 32 + sc;

    // fragment read offsets (u16 elems). A[m=l&31][k=hi*8+j], slab rows 64B.
    const int fA = (wr * 64 + ln) * 32 + hi * 8;
    const int fB = (wc * 64 + ln) * 32 + hi * 8;

    // acc init = bias (constant down a column; col = wc*64 + j*32 + ln)
    f32x16 acc00, acc01, acc10, acc11;
    {
        float bv0 = bias_il[n0 + wc * 64 + ln];
        float bv1 = bias_il[n0 + wc * 64 + 32 + ln];
#pragma unroll
        for (int r = 0; r < 16; r++) {
            acc00[r] = bv0; acc10[r] = bv0;
            acc01[r] = bv1; acc11[r] = bv1;
        }
    }

#define COMPUTE(Asb, Bsb)                                                     \
    {                                                                         \
        _Pragma("unroll") for (int s = 0; s < 2; s++) {                       \
            bf16x8 a0 = *(const bf16x8*)(Asb + fA + s * 16);                  \
            bf16x8 a1 = *(const bf16x8*)(Asb + fA + 1024 + s * 16);           \
            bf16x8 b0 = *(const bf16x8*)(Bsb + fB + s * 16);                  \
            bf16x8 b1 = *(const bf16x8*)(Bsb + fB + 1024 + s * 16);           \
            acc00 = __builtin_amdgcn_mfma_f32_32x32x16_bf16(a0, b0, acc00, 0, 0, 0); \
            acc01 = __builtin_amdgcn_mfma_f32_32x32x16_bf16(a0, b1, acc01, 0, 0, 0); \
            acc10 = __builtin_amdgcn_mfma_f32_32x32x16_bf16(a1, b0, acc10, 0, 0, 0); \
            acc11 = __builtin_amdgcn_mfma_f32_32x32x16_bf16(a1, b1, acc11, 0, 0, 0); \
        }                                                                     \
    }

    for (int k0 = 0; k0 < K_DIM; k0 += BK) {
        __syncthreads();                    // prior frag reads complete
        async16(Ag0 + k0, AsL + soff);
        async16(Ag1 + k0, AsL + soff + SL);
        async16(Ag0 + k0 + 32, AsH + soff);
        async16(Ag1 + k0 + 32, AsH + soff + SL);
        async16(Bg0 + k0, BsL + soff);
        async16(Bg1 + k0, BsL + soff + SL);
        async16(Bg0 + k0 + 32, BsH + soff);
        async16(Bg1 + k0 + 32, BsH + soff + SL);
        __syncthreads();                    // drain -> both slabs visible
        COMPUTE(AsL, BsL);
        COMPUTE(AsH, BsH);
    }
#undef COMPUTE

    // ---- fused LSTM epilogue (2 phases, one per j) ----
    // 32x32 C/D: col = lane&31, row = (reg&3) + 8*(reg>>2) + 4*(lane>>5)
    // [m74/m101-verified]
    const int row = t >> 1;     // 0..127
    const int hh = t & 1;       // 0 -> wc=0 cols, 1 -> wc=1 cols
    const size_t orow = (size_t)(m0 + row) * H_DIM;

    // prefetch epilogue operands; latency hides under the LDS phases
    float4 pc[2][2], mk[2][2];
#pragma unroll
    for (int j = 0; j < 2; j++) {
        const int hb = (n0 >> 2) + hh * 16 + j * 8;
        pc[j][0] = *(const float4*)(pre_cell + orow + hb);
        pc[j][1] = *(const float4*)(pre_cell + orow + hb + 4);
        mk[j][0] = *(const float4*)(mask + orow + hb);
        mk[j][1] = *(const float4*)(mask + orow + hb + 4);
    }

#pragma unroll
    for (int j = 0; j < 2; j++) {
        __syncthreads();        // et aliases staging / prior phase reads done
        const f32x16* aj0 = (j == 0) ? &acc00 : &acc01;   // i = 0
        const f32x16* aj1 = (j == 0) ? &acc10 : &acc11;   // i = 1
#pragma unroll
        for (int reg = 0; reg < 16; reg++) {
            int rr = (reg & 3) + 8 * (reg >> 2) + 4 * hi;
            et[(wr * 64 + rr) * 65 + wc * 32 + ln] = (*aj0)[reg];
            et[(wr * 64 + 32 + rr) * 65 + wc * 32 + ln] = (*aj1)[reg];
        }
        __syncthreads();
        const int hb = (n0 >> 2) + hh * 16 + j * 8;
        const float* ep = et + row * 65 + hh * 32;   // 8h x 4gates = 32 f32
        const float* ppc0 = (const float*)&pc[j][0];
        const float* ppc1 = (const float*)&pc[j][1];
        const float* pmk0 = (const float*)&mk[j][0];
        const float* pmk1 = (const float*)&mk[j][1];
        float4 oh0, oh1, oc0, oc1;
        float* poh0 = (float*)&oh0;
        float* poh1 = (float*)&oh1;
        float* poc0 = (float*)&oc0;
        float* poc1 = (float*)&oc1;
#pragma unroll
        for (int q = 0; q < 4; q++) {
            float fv = sigmoid_f(ep[4 * q + 0]);
            float iv = sigmoid_f(ep[4 * q + 1]);
            float ov = sigmoid_f(ep[4 * q + 2]);
            float gv = tanh_f(ep[4 * q + 3]);
            float cv = ppc0[q] * fv + iv * gv;
            poc0[q] = cv;
            poh0[q] = ov * tanh_f(cv) * pmk0[q];
        }
#pragma unroll
        for (int q = 0; q < 4; q++) {
            float fv = sigmoid_f(ep[16 + 4 * q + 0]);
            float iv = sigmoid_f(ep[16 + 4 * q + 1]);
            float ov = sigmoid_f(ep[16 + 4 * q + 2]);
            float gv = tanh_f(ep[16 + 4 * q + 3]);
            float cv = ppc1[q] * fv + iv * gv;
            poc1[q] = cv;
            poh1[q] = ov * tanh_f(cv) * pmk1[q];
        }
        float* outh = out + orow + hb;
        float* outc = out + (size_t)B_DIM * H_DIM + orow + hb;
        *(float4*)(outh) = oh0;
        *(float4*)(outh + 4) = oh1;
        *(float4*)(outc) = oc0;
        *(float4*)(outc + 4) = oc1;
    }
}

// ---------------------------------------------------------------------------
extern "C" void kernel_launch(void* const* d_in, const int* in_sizes, int n_in,
                              void* d_out, int out_size, void* d_ws, size_t ws_size,
                              hipStream_t stream) {
    const float* input    = (const float*)d_in[0];
    const float* hidden   = (const float*)d_in[1];
    const float* pre_cell = (const float*)d_in[2];
    const float* w_i = (const float*)d_in[3];
    const float* w_f = (const float*)d_in[4];
    const float* w_o = (const float*)d_in[5];
    const float* w_c = (const float*)d_in[6];
    const float* u_i = (const float*)d_in[7];
    const float* u_f = (const float*)d_in[8];
    const float* u_o = (const float*)d_in[9];
    const float* u_c = (const float*)d_in[10];
    const float* b1  = (const float*)d_in[11];
    const float* b2  = (const float*)d_in[12];
    const float* b3  = (const float*)d_in[13];
    const float* b4  = (const float*)d_in[14];
    const float* mask = (const float*)d_in[15];
    float* out = (float*)d_out;

    // workspace: A bf16 (8 MiB) | Bt bf16 (16 MiB) | bias_il (16 KiB)
    char* ws = (char*)d_ws;
    u16*   A       = (u16*)ws;
    u16*   Bt      = (u16*)(ws + (size_t)8 * 1024 * 1024);
    float* bias_il = (float*)(ws + (size_t)24 * 1024 * 1024);

    pack_all<<<dim3(4096 + 4096 + 16), dim3(256), 0, stream>>>(
        input, hidden, w_f, w_i, w_o, w_c, u_f, u_i, u_o, u_c,
        b1, b2, b3, b4, A, Bt, bias_il);
    gemm_fused<<<dim3(N_DIM / BN, B_DIM / BM), dim3(256), 0, stream>>>(
        A, Bt, bias_il, pre_cell, mask, out);
}

// Round 7
// 164.640 us; speedup vs baseline: 1.0588x; 1.0588x over previous
//
#include <hip/hip_runtime.h>
#include <hip/hip_bf16.h>
#include <cstdint>

// Problem constants
#define B_DIM 2048
#define H_DIM 1024
#define K_DIM 2048   // 2*H  (input | hidden)
#define N_DIM 4096   // 4*H  (gates, interleaved n' = 4*h + gate)

typedef unsigned short u16;
typedef __attribute__((ext_vector_type(8))) short bf16x8;
typedef __attribute__((ext_vector_type(8))) unsigned short u16x8;
typedef __attribute__((ext_vector_type(4))) float f32x4;

__device__ __forceinline__ u16 f2bf(float f) {
    unsigned int u = __float_as_uint(f);
    u += 0x7FFFu + ((u >> 16) & 1u);   // round-to-nearest-even
    return (u16)(u >> 16);
}

__device__ __forceinline__ float sigmoid_f(float x) {
    return 1.0f / (1.0f + __expf(-x));
}

// tanh via exp, saturating form (no inf/inf NaN at large |x|)
__device__ __forceinline__ float tanh_f(float x) {
    float e = __expf(2.0f * x);
    return 1.0f - 2.0f / (e + 1.0f);
}

// async global->LDS 16B per lane. LDS dest is wave-uniform base + lane*16.
__device__ __forceinline__ void async16(const u16* g, u16* l) {
    __builtin_amdgcn_global_load_lds(
        (const __attribute__((address_space(1))) unsigned int*)g,
        (__attribute__((address_space(3))) unsigned int*)l,
        16, 0, 0);
}

// ---------------------------------------------------------------------------
// Kernel 1: all packing in ONE launch.
// Region A (blocks 0..4095):        A = [input|hidden] bf16 2048x2048
// Region B (blocks 4096..8191):     Bt[n'][k], n' = 4h+g (f,i,o,c)
// Region bias (blocks 8192..8207):  bias_il[4h+g] = b_g[h]
// ---------------------------------------------------------------------------
__global__ __launch_bounds__(256) void pack_all(
    const float* __restrict__ input, const float* __restrict__ hidden,
    const float* __restrict__ w_f, const float* __restrict__ w_i,
    const float* __restrict__ w_o, const float* __restrict__ w_c,
    const float* __restrict__ u_f, const float* __restrict__ u_i,
    const float* __restrict__ u_o, const float* __restrict__ u_c,
    const float* __restrict__ b1, const float* __restrict__ b2,
    const float* __restrict__ b3, const float* __restrict__ b4,
    u16* __restrict__ A, u16* __restrict__ Bt, float* __restrict__ bias_il) {
    __shared__ float tile[32][65];
    const int blk = blockIdx.x;
    const int t = threadIdx.x;

    if (blk < 4096) {
        // ---- pack_A ----
        int idx = (blk * 256 + t) * 4;
        int m = idx >> 11;
        int k = idx & (K_DIM - 1);
        const float* src = (k < H_DIM) ? (input + (size_t)m * H_DIM + k)
                                       : (hidden + (size_t)m * H_DIM + (k - H_DIM));
        float4 v = *(const float4*)src;
        ushort4 o;
        o.x = f2bf(v.x); o.y = f2bf(v.y); o.z = f2bf(v.z); o.w = f2bf(v.w);
        *(ushort4*)(A + idx) = o;
    } else if (blk < 8192) {
        // ---- pack_B: 32h x 64k tile transpose ----
        int b2i = blk - 4096;
        int z = b2i >> 9;
        int rem = b2i & 511;
        int hx = rem & 31;
        int ky = rem >> 5;
        const float* M;
        switch (z) {
            case 0: M = w_f; break;
            case 1: M = w_i; break;
            case 2: M = w_o; break;
            case 3: M = w_c; break;
            case 4: M = u_f; break;
            case 5: M = u_i; break;
            case 6: M = u_o; break;
            default: M = u_c; break;
        }
        const int g = z & 3;
        const int half = z >> 2;
        const int h0 = hx * 32;
        const int k0 = ky * 64;
#pragma unroll
        for (int it = 0; it < 2; it++) {
            int kl = (t >> 3) + it * 32;
            int hl = (t & 7) * 4;
            float4 v = *(const float4*)(M + (size_t)(k0 + kl) * H_DIM + h0 + hl);
            tile[hl + 0][kl] = v.x;
            tile[hl + 1][kl] = v.y;
            tile[hl + 2][kl] = v.z;
            tile[hl + 3][kl] = v.w;
        }
        __syncthreads();
        int hl = t >> 3;
        int ko = (t & 7) * 8;
        u16x8 o;
#pragma unroll
        for (int q = 0; q < 8; q++) o[q] = f2bf(tile[hl][ko + q]);
        size_t n = 4 * (size_t)(h0 + hl) + g;
        *(u16x8*)(Bt + n * K_DIM + half * H_DIM + k0 + ko) = o;
    } else {
        // ---- pack_bias ----
        int idx = (blk - 8192) * 256 + t;
        int h = idx >> 2, g = idx & 3;
        const float* b = (g == 0) ? b1 : (g == 1) ? b2 : (g == 2) ? b3 : b4;
        bias_il[idx] = b[h];
    }
}

// ---------------------------------------------------------------------------
// Kernel 2: fused GEMM + LSTM epilogue.  BM=BN=128, BK=128 (FOUR 32-k slab
// pairs per barrier pair -> 16 iterations, 16 vmcnt drains vs R5's 32).
// MFMA 16x16x32 with the R5 fragment layout (provably bank-balanced: all 8
// 4-dword bank starts used equally; R6's 32x32 layout covered only 16 banks
// -> +8.4M conflict cycles, reverted). Barrier shape: stage -> barrier ->
// compute -> barrier (R4's issue/drain separation broke correctness).
// Occupancy note: 64KB LDS still allows 2 blocks/CU; grid=512 caps at 2
// anyway, so m132's BK=128 occupancy penalty does not apply here.
// ---------------------------------------------------------------------------
#define BM 128
#define BN 128
#define BK 128
#define SL (64 * 32)   // u16 elements per half-slab issue offset

__global__ __launch_bounds__(256, 2) void gemm_fused(
    const u16* __restrict__ A, const u16* __restrict__ Bt,
    const float* __restrict__ bias_il, const float* __restrict__ pre_cell,
    const float* __restrict__ mask, float* __restrict__ out) {
    __shared__ char smem[65536];
    // A slabs: smem + s*8KB (s=0..3); B slabs: smem + 32KB + s*8KB
    float* et = (float*)smem;              // epilogue reuse: [128][33] f32

    const int t = threadIdx.x;
    const int w = t >> 6, l = t & 63;
    const int m0 = blockIdx.y * BM;
    const int n0 = blockIdx.x * BN;
    const int wr = w >> 1;    // wave row in 2x2
    const int wc = w & 1;     // wave col
    const int lrow = l & 15;
    const int quad = l >> 4;

    // staging: lane l of wave w covers row w*16+(l>>2) (+64 for 2nd issue),
    // k-offset (l&3)*8 within a 32-k slab. LDS addr = uniform base + 16*lane.
    const int sr = w * 16 + (l >> 2);
    const int sc = (l & 3) * 8;
    const u16* Ag0 = A + (size_t)(m0 + sr) * K_DIM + sc;
    const u16* Ag1 = Ag0 + (size_t)64 * K_DIM;
    const u16* Bg0 = Bt + (size_t)(n0 + sr) * K_DIM + sc;
    const u16* Bg1 = Bg0 + (size_t)64 * K_DIM;
    const int soff = sr * 32 + sc;

    const int foA = (wr * 64 + lrow) * 32 + quad * 8;
    const int foB = (wc * 64 + lrow) * 32 + quad * 8;

    // acc init = bias (constant down a column)
    f32x4 acc[4][4];
#pragma unroll
    for (int j = 0; j < 4; j++) {
        float bv = bias_il[n0 + wc * 64 + j * 16 + lrow];
#pragma unroll
        for (int i = 0; i < 4; i++) acc[i][j] = (f32x4){bv, bv, bv, bv};
    }

#define COMPUTE(Asb, Bsb)                                                   \
    {                                                                       \
        bf16x8 af[4], bf[4];                                                \
        _Pragma("unroll") for (int i = 0; i < 4; i++)                       \
            af[i] = *(const bf16x8*)((Asb) + foA + i * 16 * 32);            \
        _Pragma("unroll") for (int j = 0; j < 4; j++)                       \
            bf[j] = *(const bf16x8*)((Bsb) + foB + j * 16 * 32);            \
        _Pragma("unroll") for (int i = 0; i < 4; i++)                       \
            _Pragma("unroll") for (int j = 0; j < 4; j++)                   \
                acc[i][j] = __builtin_amdgcn_mfma_f32_16x16x32_bf16(        \
                    af[i], bf[j], acc[i][j], 0, 0, 0);                      \
    }

    for (int k0 = 0; k0 < K_DIM; k0 += BK) {
        __syncthreads();                    // prior frag reads complete
#pragma unroll
        for (int s = 0; s < 4; s++) {
            u16* Asl = (u16*)(smem + s * 8192);
            u16* Bsl = (u16*)(smem + 32768 + s * 8192);
            async16(Ag0 + k0 + s * 32, Asl + soff);
            async16(Ag1 + k0 + s * 32, Asl + soff + SL);
            async16(Bg0 + k0 + s * 32, Bsl + soff);
            async16(Bg1 + k0 + s * 32, Bsl + soff + SL);
        }
        __syncthreads();                    // drain -> all 4 slab pairs visible
#pragma unroll
        for (int s = 0; s < 4; s++) {
            const u16* Asl = (const u16*)(smem + s * 8192);
            const u16* Bsl = (const u16*)(smem + 32768 + s * 8192);
            COMPUTE(Asl, Bsl);
        }
    }
#undef COMPUTE

    // ---- fused LSTM epilogue ----
    // C/D layout: col = lane&15, row = quad*4 + reg  [m89/m91-verified]
    const int row = t >> 1;     // 0..127
    const int half = t & 1;     // 0 -> wc=0 cols, 1 -> wc=1 cols
    const size_t orow = (size_t)(m0 + row) * H_DIM;

    // prefetch epilogue operands now; latency hides under the 4 LDS phases
    float4 pc[4], mk[4];
#pragma unroll
    for (int j = 0; j < 4; j++) {
        const int hg0 = (n0 >> 2) + half * 16 + j * 4;
        pc[j] = *(const float4*)(pre_cell + orow + hg0);
        mk[j] = *(const float4*)(mask + orow + hg0);
    }

#pragma unroll
    for (int j = 0; j < 4; j++) {
        __syncthreads();        // et aliases staging; prior reads complete
#pragma unroll
        for (int i = 0; i < 4; i++)
#pragma unroll
            for (int r = 0; r < 4; r++)
                et[(wr * 64 + i * 16 + quad * 4 + r) * 33 + wc * 16 + lrow] =
                    acc[i][j][r];
        __syncthreads();
        const int hg0 = (n0 >> 2) + half * 16 + j * 4;
        const float* ep = et + row * 33 + half * 16;  // 4h x 4gates = 16 f32
        const float* ppc = (const float*)&pc[j];
        const float* pmk = (const float*)&mk[j];
        float4 oh, oc;
        float* poh = (float*)&oh;
        float* poc = (float*)&oc;
#pragma unroll
        for (int q = 0; q < 4; q++) {
            float fv = sigmoid_f(ep[4 * q + 0]);
            float iv = sigmoid_f(ep[4 * q + 1]);
            float ov = sigmoid_f(ep[4 * q + 2]);
            float gv = tanh_f(ep[4 * q + 3]);
            float cv = ppc[q] * fv + iv * gv;
            poc[q] = cv;
            poh[q] = ov * tanh_f(cv) * pmk[q];
        }
        *(float4*)(out + orow + hg0) = oh;
        *(float4*)(out + (size_t)B_DIM * H_DIM + orow + hg0) = oc;
    }
}

// ---------------------------------------------------------------------------
extern "C" void kernel_launch(void* const* d_in, const int* in_sizes, int n_in,
                              void* d_out, int out_size, void* d_ws, size_t ws_size,
                              hipStream_t stream) {
    const float* input    = (const float*)d_in[0];
    const float* hidden   = (const float*)d_in[1];
    const float* pre_cell = (const float*)d_in[2];
    const float* w_i = (const float*)d_in[3];
    const float* w_f = (const float*)d_in[4];
    const float* w_o = (const float*)d_in[5];
    const float* w_c = (const float*)d_in[6];
    const float* u_i = (const float*)d_in[7];
    const float* u_f = (const float*)d_in[8];
    const float* u_o = (const float*)d_in[9];
    const float* u_c = (const float*)d_in[10];
    const float* b1  = (const float*)d_in[11];
    const float* b2  = (const float*)d_in[12];
    const float* b3  = (const float*)d_in[13];
    const float* b4  = (const float*)d_in[14];
    const float* mask = (const float*)d_in[15];
    float* out = (float*)d_out;

    // workspace: A bf16 (8 MiB) | Bt bf16 (16 MiB) | bias_il (16 KiB)
    char* ws = (char*)d_ws;
    u16*   A       = (u16*)ws;
    u16*   Bt      = (u16*)(ws + (size_t)8 * 1024 * 1024);
    float* bias_il = (float*)(ws + (size_t)24 * 1024 * 1024);

    pack_all<<<dim3(4096 + 4096 + 16), dim3(256), 0, stream>>>(
        input, hidden, w_f, w_i, w_o, w_c, u_f, u_i, u_o, u_c,
        b1, b2, b3, b4, A, Bt, bias_il);
    gemm_fused<<<dim3(N_DIM / BN, B_DIM / BM), dim3(256), 0, stream>>>(
        A, Bt, bias_il, pre_cell, mask, out);
}